// Round 5
// baseline (334.212 us; speedup 1.0000x reference)
//
#include <hip/hip_runtime.h>
#include <stdint.h>

typedef unsigned short u16;
typedef unsigned int u32;
typedef __attribute__((ext_vector_type(8))) short short8;
typedef __attribute__((ext_vector_type(4))) short short4v;
typedef __attribute__((ext_vector_type(4))) float f32x4;

#define HW 64
#define CH 256
#define NIMG 16
#define NPIX (NIMG*HW*HW)   // 65536 pixels

static __device__ __forceinline__ u16 f2bf(float f){
  u32 u = __float_as_uint(f);
  u32 r = u + 0x7FFFu + ((u >> 16) & 1u);   // RNE
  return (u16)(r >> 16);
}
static __device__ __forceinline__ float bf2f(u16 h){
  return __uint_as_float(((u32)h) << 16);
}
static __device__ __forceinline__ u32 relu_pk(u32 w){   // relu two packed bf16
  u32 lo = (w & 0x00008000u) ? 0u : (w & 0x0000FFFFu);
  u32 hi = (w & 0x80000000u) ? 0u : (w & 0xFFFF0000u);
  return lo | hi;
}

// raw barrier: LDS-visibility wait only; global loads stay in flight (no vmcnt drain)
#define BARRIER_KEEP_VMEM() do { \
  asm volatile("s_waitcnt lgkmcnt(0)" ::: "memory"); \
  __builtin_amdgcn_s_barrier(); \
} while (0)

// ---------------- weight prep: W1T[j][c], W2T[j][tap][c], bf16 ----------------
__global__ void k_prep(const float* __restrict__ w1, const float* __restrict__ w2,
                       u16* __restrict__ W1T, u16* __restrict__ W2T){
  int idx = blockIdx.x*256 + threadIdx.x;   // 640*256 = 163840 exactly
  if (idx < 16384){
    int j = idx >> 8, c = idx & 255;
    W1T[idx] = f2bf(w1[c*64 + j]);          // w1 is (1,1,256,64) -> [c][j]
  } else {
    int o = idx - 16384;
    int j = o / 2304;
    int rem = o - j*2304;
    int tap = rem >> 8, c = rem & 255;
    W2T[o] = f2bf(w2[(tap*256 + c)*64 + j]); // w2 is (3,3,256,64) -> [tap][c][j]
  }
}

// ---------------- phase 1: fused 4-step pointwise gradual update ----------------
__global__ __launch_bounds__(256) void k_phase1(const float* __restrict__ x,
    const u16* __restrict__ W1T, const float* __restrict__ b1, u16* __restrict__ B){
  __shared__ u16 At[64*264];    // 64 px x 256 ch (+8 pad)  33792 B
  __shared__ u16 Ws[64*264];    // W1T staged [n][k] (+8)   33792 B
  const int tid = threadIdx.x;
  const long pbase = (long)blockIdx.x * 64;

  #pragma unroll
  for (int it=0; it<16; ++it){
    int idx = it*256 + tid;
    int px = idx >> 6;
    int c4 = (idx & 63) << 2;
    const float4 v = *(const float4*)(x + (pbase + px)*CH + c4);
    short4v s;
    s[0] = (short)f2bf(v.x); s[1] = (short)f2bf(v.y);
    s[2] = (short)f2bf(v.z); s[3] = (short)f2bf(v.w);
    *(short4v*)&At[px*264 + c4] = s;
  }
  #pragma unroll
  for (int it=0; it<8; ++it){
    int idx = it*256 + tid;
    int n = idx >> 5;
    int c8 = (idx & 31) << 3;
    *(uint4*)&Ws[n*264 + c8] = *(const uint4*)&W1T[n*256 + c8];
  }
  __syncthreads();

  const int wave = tid >> 6, lane = tid & 63;
  const int m = lane & 15, quad = lane >> 4;
  const int abase = (wave*16 + m)*264 + quad*8;
  int bbase[4];
  #pragma unroll
  for (int nt=0; nt<4; ++nt) bbase[nt] = (nt*16 + m)*264 + quad*8;
  float b1v[4];
  #pragma unroll
  for (int nt=0; nt<4; ++nt) b1v[nt] = b1[nt*16 + m];

  for (int stepi=0; stepi<4; ++stepi){
    f32x4 acc[4];
    #pragma unroll
    for (int b=0;b<4;++b) acc[b] = 0.f;
    #pragma unroll
    for (int kk=0; kk<8; ++kk){
      const int ko = kk*32;
      short8 af = *(const short8*)&At[abase + ko];
      short8 bf[4];
      #pragma unroll
      for (int nt=0; nt<4; ++nt) bf[nt] = *(const short8*)&Ws[bbase[nt] + ko];
      #pragma unroll
      for (int nt=0; nt<4; ++nt)
        acc[nt] = __builtin_amdgcn_mfma_f32_16x16x32_bf16(af, bf[nt], acc[nt], 0,0,0);
    }
    #pragma unroll
    for (int nt=0; nt<4; ++nt){
      #pragma unroll
      for (int r=0; r<4; ++r){
        int px = wave*16 + quad*4 + r;
        At[px*264 + stepi*64 + nt*16 + m] = f2bf(acc[nt][r] + b1v[nt]);
      }
    }
    // no barrier: each wave reads/writes only its own 16 px
  }
  __syncthreads();
  #pragma unroll
  for (int it=0; it<16; ++it){
    int idx = it*256 + tid;
    int px = idx >> 6;
    int c4 = (idx & 63) << 2;
    uint2 v = *(const uint2*)&At[px*264 + c4];
    v.x = relu_pk(v.x); v.y = relu_pk(v.y);
    *(uint2*)&B[(pbase + px)*CH + c4] = v;
  }
}

// ---------------- phase 2: one 3x3 gradual-update step (launched 4x) ----------------
// 16x16 px tiles, 256 blocks, 512 threads (8 waves).
// Quarter-granular staging: Ws holds ALL 9 taps of one 64-ch input quarter
// (576 rows, single-buffered) -> barriers drop 15 -> 9, and next-quarter
// Ws/As loads get a full quarter (~3 segs) of flight before their LDS store.
// Row stride padded 72 -> 76 u16 (152 B): af/bf reads go 4-way -> <=2-way
// bank aliasing (free). LDS = 49248 + 87552 = 136.8 KB.
__global__ __launch_bounds__(512) void k_phase2(const u16* __restrict__ B,
    u16* __restrict__ Bout, const u16* __restrict__ W2T, const float* __restrict__ b2,
    const int step){
  __shared__ u16 As[324*76];      // 18x18 halo px x 64 ch (stride 76)  49248 B
  __shared__ u16 Ws[576*76];      // [tap][n] x 64 ch (stride 76)       87552 B
  const int tid = threadIdx.x;
  const int bid = blockIdx.x;
  const int img = bid >> 4;
  const int R0 = ((bid >> 2) & 3) * 16;
  const int C0 = (bid & 3) * 16;

  const int wave = tid >> 6, lane = tid & 63;
  const int m = lane & 15, quad = lane >> 4;

  uint4 ra[6], rw[9];

  auto load_as = [&](int q, uint4* r4){
    #pragma unroll
    for (int it=0; it<6; ++it){
      int idx = it*512 + tid;
      uint4 v = make_uint4(0u,0u,0u,0u);
      if (idx < 2592){
        int px = idx >> 3, ck = idx & 7;
        int hr = px / 18, hc = px - hr*18;
        int r = R0 + hr - 1, c = C0 + hc - 1;
        if ((unsigned)r < 64u && (unsigned)c < 64u){
          const u16* src = (q < step) ? Bout : B;   // B already relu'd by phase1
          v = *(const uint4*)&src[((((size_t)img*64)+r)*64 + c)*CH + q*64 + ck*8];
        }
      }
      r4[it] = v;
    }
  };
  auto store_as = [&](const uint4* r4){
    #pragma unroll
    for (int it=0; it<6; ++it){
      int idx = it*512 + tid;
      if (idx < 2592){
        int px = idx >> 3, ck = idx & 7;
        *(uint4*)&As[px*76 + ck*8] = r4[it];
      }
    }
  };
  // full quarter of weights: 576 rows (tap = dr*3+dc in 0..8, n in 0..63)
  auto load_ws = [&](int q, uint4* r4){
    #pragma unroll
    for (int it=0; it<9; ++it){
      int idx = it*512 + tid;                  // 4608 exact
      int rr = idx >> 3, ck = idx & 7;         // rr = tap*64 + n
      int tap = rr >> 6, n = rr & 63;
      r4[it] = *(const uint4*)&W2T[(size_t)n*2304 + tap*256 + q*64 + ck*8];
    }
  };
  auto store_ws = [&](const uint4* r4){
    #pragma unroll
    for (int it=0; it<9; ++it){
      int idx = it*512 + tid;
      int rr = idx >> 3, ck = idx & 7;
      *(uint4*)&Ws[rr*76 + ck*8] = r4[it];
    }
  };

  // prologue: stage quarter 0
  load_as(0, ra);  store_as(ra);
  load_ws(0, rw);  store_ws(rw);
  __syncthreads();

  f32x4 acc[2][4];
  #pragma unroll
  for (int a=0;a<2;++a){
    #pragma unroll
    for (int b=0;b<4;++b) acc[a][b] = 0.f;
  }

  for (int q = 0; q < 4; ++q){
    // issue next quarter's loads: a full quarter of flight before the stores
    if (q < 3){ load_as(q+1, ra); load_ws(q+1, rw); }

    // compute all 9 taps x 2 kk for this quarter (no barriers inside)
    #pragma unroll
    for (int dr=0; dr<3; ++dr){
      #pragma unroll
      for (int dc=0; dc<3; ++dc){
        #pragma unroll
        for (int kk=0; kk<2; ++kk){
          short8 af[2], bf[4];
          #pragma unroll
          for (int mt=0; mt<2; ++mt){
            int rt = wave + mt*8;
            af[mt] = *(const short8*)&As[((rt+dr)*18 + m + dc)*76 + kk*32 + quad*8];
          }
          #pragma unroll
          for (int nt=0; nt<4; ++nt)
            bf[nt] = *(const short8*)&Ws[((dr*3 + dc)*64 + nt*16 + m)*76 + kk*32 + quad*8];
          #pragma unroll
          for (int mt=0; mt<2; ++mt){
            #pragma unroll
            for (int nt=0; nt<4; ++nt)
              acc[mt][nt] = __builtin_amdgcn_mfma_f32_16x16x32_bf16(af[mt], bf[nt], acc[mt][nt], 0,0,0);
          }
        }
      }
    }

    BARRIER_KEEP_VMEM();               // all waves done reading As(q), Ws(q)
    if (q < 3){
      store_as(ra);                    // vmcnt counted by compiler
      store_ws(rw);
      BARRIER_KEEP_VMEM();             // staged data visible before compute(q+1)
    }
  }

  float b2v[4];
  #pragma unroll
  for (int nt=0; nt<4; ++nt) b2v[nt] = b2[nt*16 + m];
  #pragma unroll
  for (int mt=0; mt<2; ++mt){
    #pragma unroll
    for (int nt=0; nt<4; ++nt){
      #pragma unroll
      for (int r=0; r<4; ++r){
        int row = R0 + wave + mt*8;
        int col = C0 + quad*4 + r;
        size_t gi = ((((size_t)img*64 + row)*64) + col)*CH + step*64 + nt*16 + m;
        Bout[gi] = f2bf(acc[mt][nt][r] + b2v[nt]);
      }
    }
  }
}

// ---------------- phase 3: per-pixel affine recurrence + residual ----------------
// 8 lanes per pixel, 32 channels each (affine-scan parallelization).
__global__ __launch_bounds__(256) void k_phase3(const u16* __restrict__ Bout,
    const float* __restrict__ w3, const float* __restrict__ b3,
    const float* __restrict__ x, float* __restrict__ out){
  __shared__ float w3s[8*33];   // stride-33 pad: 8 segs -> 8 distinct banks
  const int tid = threadIdx.x;
  {
    int sseg = tid >> 5, c = tid & 31;
    w3s[sseg*33 + c] = w3[tid];
  }
  const float b3v = b3[0];
  __syncthreads();

  const int g   = blockIdx.x*256 + tid;   // 2048 blocks * 256 = 8*NPIX
  const int px  = g >> 3;
  const int seg = g & 7;
  const size_t cbase = (size_t)px*CH + seg*32;
  const float* wseg = &w3s[seg*33];

  uint4 d[4];
  #pragma unroll
  for (int i=0; i<4; ++i){
    uint4 v = *(const uint4*)&Bout[cbase + i*8];
    v.x = relu_pk(v.x); v.y = relu_pk(v.y); v.z = relu_pk(v.z); v.w = relu_pk(v.w);
    d[i] = v;
  }

  float s0=0.f, s1=0.f;
  #pragma unroll
  for (int i=0; i<4; ++i){
    const u32* p = (const u32*)&d[i];
    #pragma unroll
    for (int k=0; k<4; ++k){
      u32 w = p[k];
      int c = i*8 + k*2;
      s0 += bf2f((u16)(w & 0xFFFF)) * wseg[c];
      s1 += bf2f((u16)(w >> 16))    * wseg[c+1];
    }
  }
  float dot = s0 + s1;
  dot += __shfl_xor(dot, 1, 8);
  dot += __shfl_xor(dot, 2, 8);
  dot += __shfl_xor(dot, 4, 8);
  const float S0 = b3v + dot;

  float alpha = 1.f, beta = 0.f;
  #pragma unroll
  for (int i=0; i<4; ++i){
    const u32* p = (const u32*)&d[i];
    #pragma unroll
    for (int k=0; k<4; ++k){
      u32 wv = p[k];
      int c = i*8 + k*2;
      float w_a = wseg[c];
      float w_b = wseg[c+1];
      float a_a = bf2f((u16)(wv & 0xFFFF));
      float a_b = bf2f((u16)(wv >> 16));
      beta  = (1.f + w_a)*beta  - w_a*a_a;
      alpha = (1.f + w_a)*alpha;
      beta  = (1.f + w_b)*beta  - w_b*a_b;
      alpha = (1.f + w_b)*alpha;
    }
  }

  float a = alpha, b = beta;
  #pragma unroll
  for (int off=1; off<8; off<<=1){
    float pa = __shfl_up(a, off, 8);
    float pb = __shfl_up(b, off, 8);
    if (seg >= off){ b = a*pb + b; a = a*pa; }
  }
  float ea = __shfl_up(a, 1, 8);
  float eb = __shfl_up(b, 1, 8);
  float Sp = (seg == 0) ? S0 : (ea*S0 + eb);

  #pragma unroll
  for (int i=0; i<4; ++i){
    const u32* p = (const u32*)&d[i];
    float4 xv0 = *(const float4*)&x[cbase + i*8];
    float4 xv1 = *(const float4*)&x[cbase + i*8 + 4];
    float xs[8] = {xv0.x,xv0.y,xv0.z,xv0.w,xv1.x,xv1.y,xv1.z,xv1.w};
    float os[8];
    #pragma unroll
    for (int k=0; k<4; ++k){
      u32 wv = p[k];
      int c = i*8 + k*2;
      float w_a = wseg[c];
      float w_b = wseg[c+1];
      float a_a = bf2f((u16)(wv & 0xFFFF));
      float a_b = bf2f((u16)(wv >> 16));
      os[k*2]   = Sp + xs[k*2];
      Sp = (1.f + w_a)*Sp - w_a*a_a;
      os[k*2+1] = Sp + xs[k*2+1];
      Sp = (1.f + w_b)*Sp - w_b*a_b;
    }
    float4 o0, o1;
    o0.x=os[0]; o0.y=os[1]; o0.z=os[2]; o0.w=os[3];
    o1.x=os[4]; o1.y=os[5]; o1.z=os[6]; o1.w=os[7];
    *(float4*)&out[cbase + i*8]     = o0;
    *(float4*)&out[cbase + i*8 + 4] = o1;
  }
}

extern "C" void kernel_launch(void* const* d_in, const int* in_sizes, int n_in,
                              void* d_out, int out_size, void* d_ws, size_t ws_size,
                              hipStream_t stream){
  const float* x  = (const float*)d_in[0];
  const float* w1 = (const float*)d_in[1];
  const float* b1 = (const float*)d_in[2];
  const float* w2 = (const float*)d_in[3];
  const float* b2 = (const float*)d_in[4];
  const float* w3 = (const float*)d_in[5];
  const float* b3 = (const float*)d_in[6];
  float* out = (float*)d_out;

  // workspace carve: B(relu'd) 32MB | Bout 32MB | W1T 32KB | W2T 288KB
  u16* B    = (u16*)d_ws;
  u16* Bout = B    + (size_t)NPIX*CH;
  u16* W1T  = Bout + (size_t)NPIX*CH;
  u16* W2T  = W1T  + 16384;

  hipLaunchKernelGGL(k_prep,   dim3(640),  dim3(256), 0, stream, w1, w2, W1T, W2T);
  hipLaunchKernelGGL(k_phase1, dim3(1024), dim3(256), 0, stream, x, W1T, b1, B);
  for (int s = 0; s < 4; ++s)
    hipLaunchKernelGGL(k_phase2, dim3(256), dim3(512), 0, stream, B, Bout, W2T, b2, s);
  hipLaunchKernelGGL(k_phase3, dim3(2048), dim3(256), 0, stream, Bout, w3, b3, x, out);
}

// Round 6
// 258.694 us; speedup vs baseline: 1.2919x; 1.2919x over previous
//
#include <hip/hip_runtime.h>
#include <stdint.h>

typedef unsigned short u16;
typedef unsigned int u32;
typedef __attribute__((ext_vector_type(8))) short short8;
typedef __attribute__((ext_vector_type(4))) short short4v;
typedef __attribute__((ext_vector_type(4))) float f32x4;

#define HW 64
#define CH 256
#define NIMG 16
#define NPIX (NIMG*HW*HW)   // 65536 pixels

static __device__ __forceinline__ u16 f2bf(float f){
  u32 u = __float_as_uint(f);
  u32 r = u + 0x7FFFu + ((u >> 16) & 1u);   // RNE
  return (u16)(r >> 16);
}
static __device__ __forceinline__ float bf2f(u16 h){
  return __uint_as_float(((u32)h) << 16);
}
static __device__ __forceinline__ u32 relu_pk(u32 w){   // relu two packed bf16
  u32 lo = (w & 0x00008000u) ? 0u : (w & 0x0000FFFFu);
  u32 hi = (w & 0x80000000u) ? 0u : (w & 0xFFFF0000u);
  return lo | hi;
}

// LDS-visibility barrier (no vmem drain) — for mid-seg As handoff
#define BARRIER_KEEP_VMEM() do { \
  asm volatile("s_waitcnt lgkmcnt(0)" ::: "memory"); \
  __builtin_amdgcn_s_barrier(); \
} while (0)
// seg-end: drain gload_lds (vmcnt) + ds ops, then barrier. Each wave drains its
// OWN gloads; barrier release => all waves' LDS writes visible.
#define SEG_SYNC() do { \
  asm volatile("s_waitcnt vmcnt(0)" ::: "memory"); \
  asm volatile("s_waitcnt lgkmcnt(0)" ::: "memory"); \
  __builtin_amdgcn_s_barrier(); \
} while (0)

// ---------------- weight prep ----------------
// W1T[j][c] bf16.
// W2T re-laid for phase2's global_load_lds staging: 12 blocks bt=q*3+dr of
// 12288 u16; within a block, linear order (row = dc*64 + n, 16B unit u) holds
// original channels (u ^ (row&7)) -- the XOR involution is baked in here so a
// LINEAR global->LDS copy yields the swizzled layout (both-sides rule).
__global__ void k_prep(const float* __restrict__ w1, const float* __restrict__ w2,
                       u16* __restrict__ W1T, u16* __restrict__ W2T){
  int idx = blockIdx.x*256 + threadIdx.x;   // 640*256 = 163840 exactly
  if (idx < 16384){
    int j = idx >> 8, c = idx & 255;
    W1T[idx] = f2bf(w1[c*64 + j]);          // w1 is (1,1,256,64) -> [c][j]
  } else {
    int o = idx - 16384;                    // 0..147455
    int bt  = o / 12288;                    // q*3 + dr
    int rem = o - bt*12288;
    int row = rem >> 6;                     // 0..191 = dc*64 + n
    int j   = rem & 63;
    int u   = j >> 3, e = j & 7;
    int q = bt / 3, dr = bt - q*3;
    int dc = row >> 6, n = row & 63;
    int cin = q*64 + ((u ^ (row & 7)) << 3) + e;
    int tap = dr*3 + dc;
    W2T[o] = f2bf(w2[(tap*256 + cin)*64 + n]);  // w2 is (3,3,256,64)
  }
}

// ---------------- phase 1: fused 4-step pointwise gradual update ----------------
__global__ __launch_bounds__(256) void k_phase1(const float* __restrict__ x,
    const u16* __restrict__ W1T, const float* __restrict__ b1, u16* __restrict__ B){
  __shared__ u16 At[64*264];    // 64 px x 256 ch (+8 pad)  33792 B
  __shared__ u16 Ws[64*264];    // W1T staged [n][k] (+8)   33792 B
  const int tid = threadIdx.x;
  const long pbase = (long)blockIdx.x * 64;

  #pragma unroll
  for (int it=0; it<16; ++it){
    int idx = it*256 + tid;
    int px = idx >> 6;
    int c4 = (idx & 63) << 2;
    const float4 v = *(const float4*)(x + (pbase + px)*CH + c4);
    short4v s;
    s[0] = (short)f2bf(v.x); s[1] = (short)f2bf(v.y);
    s[2] = (short)f2bf(v.z); s[3] = (short)f2bf(v.w);
    *(short4v*)&At[px*264 + c4] = s;
  }
  #pragma unroll
  for (int it=0; it<8; ++it){
    int idx = it*256 + tid;
    int n = idx >> 5;
    int c8 = (idx & 31) << 3;
    *(uint4*)&Ws[n*264 + c8] = *(const uint4*)&W1T[n*256 + c8];
  }
  __syncthreads();

  const int wave = tid >> 6, lane = tid & 63;
  const int m = lane & 15, quad = lane >> 4;
  const int abase = (wave*16 + m)*264 + quad*8;
  int bbase[4];
  #pragma unroll
  for (int nt=0; nt<4; ++nt) bbase[nt] = (nt*16 + m)*264 + quad*8;
  float b1v[4];
  #pragma unroll
  for (int nt=0; nt<4; ++nt) b1v[nt] = b1[nt*16 + m];

  for (int stepi=0; stepi<4; ++stepi){
    f32x4 acc[4];
    #pragma unroll
    for (int b=0;b<4;++b) acc[b] = 0.f;
    #pragma unroll
    for (int kk=0; kk<8; ++kk){
      const int ko = kk*32;
      short8 af = *(const short8*)&At[abase + ko];
      short8 bf[4];
      #pragma unroll
      for (int nt=0; nt<4; ++nt) bf[nt] = *(const short8*)&Ws[bbase[nt] + ko];
      #pragma unroll
      for (int nt=0; nt<4; ++nt)
        acc[nt] = __builtin_amdgcn_mfma_f32_16x16x32_bf16(af, bf[nt], acc[nt], 0,0,0);
    }
    #pragma unroll
    for (int nt=0; nt<4; ++nt){
      #pragma unroll
      for (int r=0; r<4; ++r){
        int px = wave*16 + quad*4 + r;
        At[px*264 + stepi*64 + nt*16 + m] = f2bf(acc[nt][r] + b1v[nt]);
      }
    }
    // no barrier: each wave reads/writes only its own 16 px
  }
  __syncthreads();
  #pragma unroll
  for (int it=0; it<16; ++it){
    int idx = it*256 + tid;
    int px = idx >> 6;
    int c4 = (idx & 63) << 2;
    uint2 v = *(const uint2*)&At[px*264 + c4];
    v.x = relu_pk(v.x); v.y = relu_pk(v.y);
    *(uint2*)&B[(pbase + px)*CH + c4] = v;
  }
}

// ---------------- phase 2: one 3x3 gradual-update step (launched 4x) ----------------
// 16x16 px tiles, 256 blocks, 512 threads (8 waves). Round-4 pipeline with the
// weight relay replaced by global_load_lds (zero staging VGPRs / ds_writes /
// addr VALU => no spill; round-5's spill was the regression). Ws LDS is linear
// [192 rows][128 B] per buffer; bf reads XOR unit ^= (m&7) (involution baked
// into W2T by k_prep) => <=2-way aliasing (free). As keeps stride-76 padding
// (measured 0 conflicts). LDS = 49248 + 2*24576 = 96.1 KB.
__global__ __launch_bounds__(512) void k_phase2(const u16* __restrict__ B,
    u16* __restrict__ Bout, const u16* __restrict__ W2T, const float* __restrict__ b2,
    const int step){
  __shared__ u16 As[324*76];      // 18x18 halo px x 64 ch (stride 76)  49248 B
  __shared__ u16 Ws[2][192*64];   // [dc*64+n] x 64 ch, swizzled, linear 2x24576 B
  const int tid = threadIdx.x;
  const int bid = blockIdx.x;
  const int img = bid >> 4;
  const int R0 = ((bid >> 2) & 3) * 16;
  const int C0 = (bid & 3) * 16;

  const int wave = tid >> 6, lane = tid & 63;
  const int m = lane & 15, quad = lane >> 4;

  uint4 ra[6];

  auto load_as = [&](int q, uint4* r4){
    #pragma unroll
    for (int it=0; it<6; ++it){
      int idx = it*512 + tid;
      uint4 v = make_uint4(0u,0u,0u,0u);
      if (idx < 2592){
        int px = idx >> 3, ck = idx & 7;
        int hr = px / 18, hc = px - hr*18;
        int r = R0 + hr - 1, c = C0 + hc - 1;
        if ((unsigned)r < 64u && (unsigned)c < 64u){
          const u16* src = (q < step) ? Bout : B;   // B already relu'd by phase1
          v = *(const uint4*)&src[((((size_t)img*64)+r)*64 + c)*CH + q*64 + ck*8];
        }
      }
      r4[it] = v;
    }
  };
  auto store_as = [&](const uint4* r4){
    #pragma unroll
    for (int it=0; it<6; ++it){
      int idx = it*512 + tid;
      if (idx < 2592){
        int px = idx >> 3, ck = idx & 7;
        *(uint4*)&As[px*76 + ck*8] = r4[it];
      }
    }
  };
  // stage one tap-triplet (24576 B) via async global->LDS, 16B/lane.
  // LDS dest is wave-uniform base + lane*16 (linear); global src is linear too
  // (swizzle pre-baked in W2T by k_prep).
  auto gload_ws = [&](int bt, int buf){
    #pragma unroll
    for (int it=0; it<3; ++it){
      int chunk = wave*3 + it;                          // 0..23, 1024 B each
      const u16* g = W2T + (size_t)bt*12288 + chunk*512 + lane*8;
      __builtin_amdgcn_global_load_lds(
        (const __attribute__((address_space(1))) void*)g,
        (__attribute__((address_space(3))) void*)&Ws[buf][chunk*512],
        16, 0, 0);
    }
  };

  // prologue: stage seg0 weights + quarter-0 As; full drain acceptable here
  gload_ws(0, 0);
  load_as(0, ra); store_as(ra);
  __syncthreads();

  f32x4 acc[2][4];
  #pragma unroll
  for (int a=0;a<2;++a){
    #pragma unroll
    for (int b=0;b<4;++b) acc[a][b] = 0.f;
  }

  #pragma unroll
  for (int seg = 0; seg < 12; ++seg){
    const int q  = seg / 3;
    const int dr = seg % 3;

    if (seg <= 10) gload_ws(seg+1, (seg+1)&1);   // dest buf idle this seg
    if (dr == 1 && q < 3) load_as(q+1, ra);

    const u16* wsb = Ws[seg & 1];
    #pragma unroll
    for (int dc=0; dc<3; ++dc){
      #pragma unroll
      for (int kk=0; kk<2; ++kk){
        short8 af[2], bf[4];
        #pragma unroll
        for (int mt=0; mt<2; ++mt){
          int rt = wave + mt*8;
          af[mt] = *(const short8*)&As[((rt+dr)*18 + m + dc)*76 + kk*32 + quad*8];
        }
        #pragma unroll
        for (int nt=0; nt<4; ++nt){
          int row  = dc*64 + nt*16 + m;
          int unit = (kk*4 + quad) ^ (m & 7);   // row&7 == m&7
          bf[nt] = *(const short8*)&wsb[row*64 + unit*8];
        }
        #pragma unroll
        for (int mt=0; mt<2; ++mt){
          #pragma unroll
          for (int nt=0; nt<4; ++nt)
            acc[mt][nt] = __builtin_amdgcn_mfma_f32_16x16x32_bf16(af[mt], bf[nt], acc[mt][nt], 0,0,0);
        }
      }
    }

    if (dr == 2 && q < 3){
      BARRIER_KEEP_VMEM();     // all waves done reading As(q)
      store_as(ra);            // compiler vmcnt-waits on ra only
    }
    if (seg < 11) SEG_SYNC();  // next-seg Ws landed + ds stores visible
  }

  float b2v[4];
  #pragma unroll
  for (int nt=0; nt<4; ++nt) b2v[nt] = b2[nt*16 + m];
  #pragma unroll
  for (int mt=0; mt<2; ++mt){
    #pragma unroll
    for (int nt=0; nt<4; ++nt){
      #pragma unroll
      for (int r=0; r<4; ++r){
        int row = R0 + wave + mt*8;
        int col = C0 + quad*4 + r;
        size_t gi = ((((size_t)img*64 + row)*64) + col)*CH + step*64 + nt*16 + m;
        Bout[gi] = f2bf(acc[mt][nt][r] + b2v[nt]);
      }
    }
  }
}

// ---------------- phase 3: per-pixel affine recurrence + residual ----------------
// 8 lanes per pixel, 32 channels each (affine-scan parallelization).
__global__ __launch_bounds__(256) void k_phase3(const u16* __restrict__ Bout,
    const float* __restrict__ w3, const float* __restrict__ b3,
    const float* __restrict__ x, float* __restrict__ out){
  __shared__ float w3s[8*33];   // stride-33 pad: 8 segs -> 8 distinct banks
  const int tid = threadIdx.x;
  {
    int sseg = tid >> 5, c = tid & 31;
    w3s[sseg*33 + c] = w3[tid];
  }
  const float b3v = b3[0];
  __syncthreads();

  const int g   = blockIdx.x*256 + tid;   // 2048 blocks * 256 = 8*NPIX
  const int px  = g >> 3;
  const int seg = g & 7;
  const size_t cbase = (size_t)px*CH + seg*32;
  const float* wseg = &w3s[seg*33];

  uint4 d[4];
  #pragma unroll
  for (int i=0; i<4; ++i){
    uint4 v = *(const uint4*)&Bout[cbase + i*8];
    v.x = relu_pk(v.x); v.y = relu_pk(v.y); v.z = relu_pk(v.z); v.w = relu_pk(v.w);
    d[i] = v;
  }

  float s0=0.f, s1=0.f;
  #pragma unroll
  for (int i=0; i<4; ++i){
    const u32* p = (const u32*)&d[i];
    #pragma unroll
    for (int k=0; k<4; ++k){
      u32 w = p[k];
      int c = i*8 + k*2;
      s0 += bf2f((u16)(w & 0xFFFF)) * wseg[c];
      s1 += bf2f((u16)(w >> 16))    * wseg[c+1];
    }
  }
  float dot = s0 + s1;
  dot += __shfl_xor(dot, 1, 8);
  dot += __shfl_xor(dot, 2, 8);
  dot += __shfl_xor(dot, 4, 8);
  const float S0 = b3v + dot;

  float alpha = 1.f, beta = 0.f;
  #pragma unroll
  for (int i=0; i<4; ++i){
    const u32* p = (const u32*)&d[i];
    #pragma unroll
    for (int k=0; k<4; ++k){
      u32 wv = p[k];
      int c = i*8 + k*2;
      float w_a = wseg[c];
      float w_b = wseg[c+1];
      float a_a = bf2f((u16)(wv & 0xFFFF));
      float a_b = bf2f((u16)(wv >> 16));
      beta  = (1.f + w_a)*beta  - w_a*a_a;
      alpha = (1.f + w_a)*alpha;
      beta  = (1.f + w_b)*beta  - w_b*a_b;
      alpha = (1.f + w_b)*alpha;
    }
  }

  float a = alpha, b = beta;
  #pragma unroll
  for (int off=1; off<8; off<<=1){
    float pa = __shfl_up(a, off, 8);
    float pb = __shfl_up(b, off, 8);
    if (seg >= off){ b = a*pb + b; a = a*pa; }
  }
  float ea = __shfl_up(a, 1, 8);
  float eb = __shfl_up(b, 1, 8);
  float Sp = (seg == 0) ? S0 : (ea*S0 + eb);

  #pragma unroll
  for (int i=0; i<4; ++i){
    const u32* p = (const u32*)&d[i];
    float4 xv0 = *(const float4*)&x[cbase + i*8];
    float4 xv1 = *(const float4*)&x[cbase + i*8 + 4];
    float xs[8] = {xv0.x,xv0.y,xv0.z,xv0.w,xv1.x,xv1.y,xv1.z,xv1.w};
    float os[8];
    #pragma unroll
    for (int k=0; k<4; ++k){
      u32 wv = p[k];
      int c = i*8 + k*2;
      float w_a = wseg[c];
      float w_b = wseg[c+1];
      float a_a = bf2f((u16)(wv & 0xFFFF));
      float a_b = bf2f((u16)(wv >> 16));
      os[k*2]   = Sp + xs[k*2];
      Sp = (1.f + w_a)*Sp - w_a*a_a;
      os[k*2+1] = Sp + xs[k*2+1];
      Sp = (1.f + w_b)*Sp - w_b*a_b;
    }
    float4 o0, o1;
    o0.x=os[0]; o0.y=os[1]; o0.z=os[2]; o0.w=os[3];
    o1.x=os[4]; o1.y=os[5]; o1.z=os[6]; o1.w=os[7];
    *(float4*)&out[cbase + i*8]     = o0;
    *(float4*)&out[cbase + i*8 + 4] = o1;
  }
}

extern "C" void kernel_launch(void* const* d_in, const int* in_sizes, int n_in,
                              void* d_out, int out_size, void* d_ws, size_t ws_size,
                              hipStream_t stream){
  const float* x  = (const float*)d_in[0];
  const float* w1 = (const float*)d_in[1];
  const float* b1 = (const float*)d_in[2];
  const float* w2 = (const float*)d_in[3];
  const float* b2 = (const float*)d_in[4];
  const float* w3 = (const float*)d_in[5];
  const float* b3 = (const float*)d_in[6];
  float* out = (float*)d_out;

  // workspace carve: B(relu'd) 32MB | Bout 32MB | W1T 32KB | W2T 288KB
  u16* B    = (u16*)d_ws;
  u16* Bout = B    + (size_t)NPIX*CH;
  u16* W1T  = Bout + (size_t)NPIX*CH;
  u16* W2T  = W1T  + 16384;

  hipLaunchKernelGGL(k_prep,   dim3(640),  dim3(256), 0, stream, w1, w2, W1T, W2T);
  hipLaunchKernelGGL(k_phase1, dim3(1024), dim3(256), 0, stream, x, W1T, b1, B);
  for (int s = 0; s < 4; ++s)
    hipLaunchKernelGGL(k_phase2, dim3(256), dim3(512), 0, stream, B, Bout, W2T, b2, s);
  hipLaunchKernelGGL(k_phase3, dim3(2048), dim3(256), 0, stream, Bout, w3, b3, x, out);
}

// Round 7
// 248.198 us; speedup vs baseline: 1.3466x; 1.0423x over previous
//
#include <hip/hip_runtime.h>
#include <stdint.h>

typedef unsigned short u16;
typedef unsigned int u32;
typedef __attribute__((ext_vector_type(8))) short short8;
typedef __attribute__((ext_vector_type(4))) short short4v;
typedef __attribute__((ext_vector_type(4))) float f32x4;

#define HW 64
#define CH 256
#define NIMG 16
#define NPIX (NIMG*HW*HW)   // 65536 pixels

static __device__ __forceinline__ u16 f2bf(float f){
  u32 u = __float_as_uint(f);
  u32 r = u + 0x7FFFu + ((u >> 16) & 1u);   // RNE
  return (u16)(r >> 16);
}
static __device__ __forceinline__ float bf2f(u16 h){
  return __uint_as_float(((u32)h) << 16);
}
static __device__ __forceinline__ u32 relu_pk(u32 w){   // relu two packed bf16
  u32 lo = (w & 0x00008000u) ? 0u : (w & 0x0000FFFFu);
  u32 hi = (w & 0x80000000u) ? 0u : (w & 0xFFFF0000u);
  return lo | hi;
}

// LDS-visibility barrier (no vmem drain) — for mid-seg As handoff
#define BARRIER_KEEP_VMEM() do { \
  asm volatile("s_waitcnt lgkmcnt(0)" ::: "memory"); \
  __builtin_amdgcn_s_barrier(); \
} while (0)
// seg-end: drain gload_lds (vmcnt) + ds ops, then barrier. Each wave drains its
// OWN gloads; barrier release => all waves' LDS writes visible.
#define SEG_SYNC() do { \
  asm volatile("s_waitcnt vmcnt(0)" ::: "memory"); \
  asm volatile("s_waitcnt lgkmcnt(0)" ::: "memory"); \
  __builtin_amdgcn_s_barrier(); \
} while (0)

// ---------------- weight prep ----------------
// W1T[j][c] bf16.
// W2T re-laid for phase2's global_load_lds staging: 12 blocks bt=q*3+dr of
// 12288 u16; within a block, linear order (row = dc*64 + n, 16B unit u) holds
// original channels (u ^ (row&7)) -- the XOR involution is baked in here so a
// LINEAR global->LDS copy yields the swizzled layout (both-sides rule).
__global__ void k_prep(const float* __restrict__ w1, const float* __restrict__ w2,
                       u16* __restrict__ W1T, u16* __restrict__ W2T){
  int idx = blockIdx.x*256 + threadIdx.x;   // 640*256 = 163840 exactly
  if (idx < 16384){
    int j = idx >> 8, c = idx & 255;
    W1T[idx] = f2bf(w1[c*64 + j]);          // w1 is (1,1,256,64) -> [c][j]
  } else {
    int o = idx - 16384;                    // 0..147455
    int bt  = o / 12288;                    // q*3 + dr
    int rem = o - bt*12288;
    int row = rem >> 6;                     // 0..191 = dc*64 + n
    int j   = rem & 63;
    int u   = j >> 3, e = j & 7;
    int q = bt / 3, dr = bt - q*3;
    int dc = row >> 6, n = row & 63;
    int cin = q*64 + ((u ^ (row & 7)) << 3) + e;
    int tap = dr*3 + dc;
    W2T[o] = f2bf(w2[(tap*256 + cin)*64 + n]);  // w2 is (3,3,256,64)
  }
}

// ---------------- phase 1: fused 4-step pointwise gradual update ----------------
__global__ __launch_bounds__(256) void k_phase1(const float* __restrict__ x,
    const u16* __restrict__ W1T, const float* __restrict__ b1, u16* __restrict__ B){
  __shared__ u16 At[64*264];    // 64 px x 256 ch (+8 pad)  33792 B
  __shared__ u16 Ws[64*264];    // W1T staged [n][k] (+8)   33792 B
  const int tid = threadIdx.x;
  const long pbase = (long)blockIdx.x * 64;

  #pragma unroll
  for (int it=0; it<16; ++it){
    int idx = it*256 + tid;
    int px = idx >> 6;
    int c4 = (idx & 63) << 2;
    const float4 v = *(const float4*)(x + (pbase + px)*CH + c4);
    short4v s;
    s[0] = (short)f2bf(v.x); s[1] = (short)f2bf(v.y);
    s[2] = (short)f2bf(v.z); s[3] = (short)f2bf(v.w);
    *(short4v*)&At[px*264 + c4] = s;
  }
  #pragma unroll
  for (int it=0; it<8; ++it){
    int idx = it*256 + tid;
    int n = idx >> 5;
    int c8 = (idx & 31) << 3;
    *(uint4*)&Ws[n*264 + c8] = *(const uint4*)&W1T[n*256 + c8];
  }
  __syncthreads();

  const int wave = tid >> 6, lane = tid & 63;
  const int m = lane & 15, quad = lane >> 4;
  const int abase = (wave*16 + m)*264 + quad*8;
  int bbase[4];
  #pragma unroll
  for (int nt=0; nt<4; ++nt) bbase[nt] = (nt*16 + m)*264 + quad*8;
  float b1v[4];
  #pragma unroll
  for (int nt=0; nt<4; ++nt) b1v[nt] = b1[nt*16 + m];

  for (int stepi=0; stepi<4; ++stepi){
    f32x4 acc[4];
    #pragma unroll
    for (int b=0;b<4;++b) acc[b] = 0.f;
    #pragma unroll
    for (int kk=0; kk<8; ++kk){
      const int ko = kk*32;
      short8 af = *(const short8*)&At[abase + ko];
      short8 bf[4];
      #pragma unroll
      for (int nt=0; nt<4; ++nt) bf[nt] = *(const short8*)&Ws[bbase[nt] + ko];
      #pragma unroll
      for (int nt=0; nt<4; ++nt)
        acc[nt] = __builtin_amdgcn_mfma_f32_16x16x32_bf16(af, bf[nt], acc[nt], 0,0,0);
    }
    #pragma unroll
    for (int nt=0; nt<4; ++nt){
      #pragma unroll
      for (int r=0; r<4; ++r){
        int px = wave*16 + quad*4 + r;
        At[px*264 + stepi*64 + nt*16 + m] = f2bf(acc[nt][r] + b1v[nt]);
      }
    }
    // no barrier: each wave reads/writes only its own 16 px
  }
  __syncthreads();
  #pragma unroll
  for (int it=0; it<16; ++it){
    int idx = it*256 + tid;
    int px = idx >> 6;
    int c4 = (idx & 63) << 2;
    uint2 v = *(const uint2*)&At[px*264 + c4];
    v.x = relu_pk(v.x); v.y = relu_pk(v.y);
    *(uint2*)&B[(pbase + px)*CH + c4] = v;
  }
}

// ---------------- phase 2: one 3x3 gradual-update step (launched 4x) ----------------
// 16x16 px tiles, 256 blocks, 512 threads (8 waves). Round-4 pipeline with the
// weight relay replaced by global_load_lds (zero staging VGPRs / ds_writes /
// addr VALU). Ws LDS is linear [192 rows][128 B] per buffer; bf reads XOR
// unit ^= (m&7) (involution baked into W2T by k_prep) => <=2-way aliasing.
// As keeps stride-76 padding (measured 0 conflicts). LDS = 96.1 KB.
__global__ __launch_bounds__(512) void k_phase2(const u16* __restrict__ B,
    u16* __restrict__ Bout, const u16* __restrict__ W2T, const float* __restrict__ b2,
    const int step){
  __shared__ u16 As[324*76];      // 18x18 halo px x 64 ch (stride 76)  49248 B
  __shared__ u16 Ws[2][192*64];   // [dc*64+n] x 64 ch, swizzled, linear 2x24576 B
  const int tid = threadIdx.x;
  const int bid = blockIdx.x;
  const int img = bid >> 4;
  const int R0 = ((bid >> 2) & 3) * 16;
  const int C0 = (bid & 3) * 16;

  const int wave = tid >> 6, lane = tid & 63;
  const int m = lane & 15, quad = lane >> 4;

  uint4 ra[6];

  auto load_as = [&](int q, uint4* r4){
    #pragma unroll
    for (int it=0; it<6; ++it){
      int idx = it*512 + tid;
      uint4 v = make_uint4(0u,0u,0u,0u);
      if (idx < 2592){
        int px = idx >> 3, ck = idx & 7;
        int hr = px / 18, hc = px - hr*18;
        int r = R0 + hr - 1, c = C0 + hc - 1;
        if ((unsigned)r < 64u && (unsigned)c < 64u){
          const u16* src = (q < step) ? Bout : B;   // B already relu'd by phase1
          v = *(const uint4*)&src[((((size_t)img*64)+r)*64 + c)*CH + q*64 + ck*8];
        }
      }
      r4[it] = v;
    }
  };
  auto store_as = [&](const uint4* r4){
    #pragma unroll
    for (int it=0; it<6; ++it){
      int idx = it*512 + tid;
      if (idx < 2592){
        int px = idx >> 3, ck = idx & 7;
        *(uint4*)&As[px*76 + ck*8] = r4[it];
      }
    }
  };
  // stage one tap-triplet (24576 B) via async global->LDS, 16B/lane.
  auto gload_ws = [&](int bt, int buf){
    #pragma unroll
    for (int it=0; it<3; ++it){
      int chunk = wave*3 + it;                          // 0..23, 1024 B each
      const u16* g = W2T + (size_t)bt*12288 + chunk*512 + lane*8;
      __builtin_amdgcn_global_load_lds(
        (const __attribute__((address_space(1))) void*)g,
        (__attribute__((address_space(3))) void*)&Ws[buf][chunk*512],
        16, 0, 0);
    }
  };

  // prologue: stage seg0 weights + quarter-0 As; full drain acceptable here
  gload_ws(0, 0);
  load_as(0, ra); store_as(ra);
  __syncthreads();

  f32x4 acc[2][4];
  #pragma unroll
  for (int a=0;a<2;++a){
    #pragma unroll
    for (int b=0;b<4;++b) acc[a][b] = 0.f;
  }

  #pragma unroll
  for (int seg = 0; seg < 12; ++seg){
    const int q  = seg / 3;
    const int dr = seg % 3;

    if (seg <= 10) gload_ws(seg+1, (seg+1)&1);   // dest buf idle this seg
    if (dr == 1 && q < 3) load_as(q+1, ra);

    const u16* wsb = Ws[seg & 1];
    #pragma unroll
    for (int dc=0; dc<3; ++dc){
      #pragma unroll
      for (int kk=0; kk<2; ++kk){
        short8 af[2], bf[4];
        #pragma unroll
        for (int mt=0; mt<2; ++mt){
          int rt = wave + mt*8;
          af[mt] = *(const short8*)&As[((rt+dr)*18 + m + dc)*76 + kk*32 + quad*8];
        }
        #pragma unroll
        for (int nt=0; nt<4; ++nt){
          int row  = dc*64 + nt*16 + m;
          int unit = (kk*4 + quad) ^ (m & 7);   // row&7 == m&7
          bf[nt] = *(const short8*)&wsb[row*64 + unit*8];
        }
        #pragma unroll
        for (int mt=0; mt<2; ++mt){
          #pragma unroll
          for (int nt=0; nt<4; ++nt)
            acc[mt][nt] = __builtin_amdgcn_mfma_f32_16x16x32_bf16(af[mt], bf[nt], acc[mt][nt], 0,0,0);
        }
      }
    }

    if (dr == 2 && q < 3){
      BARRIER_KEEP_VMEM();     // all waves done reading As(q)
      store_as(ra);            // compiler vmcnt-waits on ra only
    }
    if (seg < 11) SEG_SYNC();  // next-seg Ws landed + ds stores visible
  }

  float b2v[4];
  #pragma unroll
  for (int nt=0; nt<4; ++nt) b2v[nt] = b2[nt*16 + m];
  #pragma unroll
  for (int mt=0; mt<2; ++mt){
    #pragma unroll
    for (int nt=0; nt<4; ++nt){
      #pragma unroll
      for (int r=0; r<4; ++r){
        int row = R0 + wave + mt*8;
        int col = C0 + quad*4 + r;
        size_t gi = ((((size_t)img*64 + row)*64) + col)*CH + step*64 + nt*16 + m;
        Bout[gi] = f2bf(acc[mt][nt][r] + b2v[nt]);
      }
    }
  }
}

// ---------------- phase 3: per-pixel affine recurrence + residual ----------------
// 16 lanes per pixel, 16 channels each (was 8x32): serial chains halve to 16
// steps, x loads hoisted to the top (6 loads in flight before the chain), grid
// 4096 blocks -> shorter waves pack the BW pipe better (was 46% peak, 60% of
// achievable; memory floor 25 us).
__global__ __launch_bounds__(256) void k_phase3(const u16* __restrict__ Bout,
    const float* __restrict__ w3, const float* __restrict__ b3,
    const float* __restrict__ x, float* __restrict__ out){
  __shared__ float w3s[16*17];  // stride-17: 17*seg distinct mod 32 -> conflict-free
  const int tid = threadIdx.x;
  {
    int sseg = tid >> 4, c = tid & 15;
    w3s[sseg*17 + c] = w3[tid];
  }
  const float b3v = b3[0];
  __syncthreads();

  const int g   = blockIdx.x*256 + tid;   // 4096 blocks * 256 = 16*NPIX
  const int px  = g >> 4;
  const int seg = g & 15;
  const size_t cbase = (size_t)px*CH + seg*16;
  const float* wseg = &w3s[seg*17];

  // load own 16 channels (relu'd) + residual x: all 6 loads issued up front
  uint4 d[2];
  #pragma unroll
  for (int i=0; i<2; ++i){
    uint4 v = *(const uint4*)&Bout[cbase + i*8];
    v.x = relu_pk(v.x); v.y = relu_pk(v.y); v.z = relu_pk(v.z); v.w = relu_pk(v.w);
    d[i] = v;
  }
  float4 xv[4];
  #pragma unroll
  for (int i=0; i<4; ++i) xv[i] = *(const float4*)&x[cbase + i*4];

  // partial dot product over own 16 channels
  float s0=0.f, s1=0.f;
  #pragma unroll
  for (int i=0; i<2; ++i){
    const u32* p = (const u32*)&d[i];
    #pragma unroll
    for (int k=0; k<4; ++k){
      u32 w = p[k];
      int c = i*8 + k*2;
      s0 += bf2f((u16)(w & 0xFFFF)) * wseg[c];
      s1 += bf2f((u16)(w >> 16))    * wseg[c+1];
    }
  }
  float dot = s0 + s1;
  dot += __shfl_xor(dot, 1, 16);
  dot += __shfl_xor(dot, 2, 16);
  dot += __shfl_xor(dot, 4, 16);
  dot += __shfl_xor(dot, 8, 16);
  const float S0 = b3v + dot;             // A'_0, same at all 16 lanes of the pixel

  // per-segment affine: S_end = alpha*S_start + beta   (16 serial steps)
  float alpha = 1.f, beta = 0.f;
  #pragma unroll
  for (int i=0; i<2; ++i){
    const u32* p = (const u32*)&d[i];
    #pragma unroll
    for (int k=0; k<4; ++k){
      u32 wv = p[k];
      int c = i*8 + k*2;
      float w_a = wseg[c];
      float w_b = wseg[c+1];
      float a_a = bf2f((u16)(wv & 0xFFFF));
      float a_b = bf2f((u16)(wv >> 16));
      beta  = (1.f + w_a)*beta  - w_a*a_a;
      alpha = (1.f + w_a)*alpha;
      beta  = (1.f + w_b)*beta  - w_b*a_b;
      alpha = (1.f + w_b)*alpha;
    }
  }

  // inclusive affine scan over the 16-lane group: P_seg = T_seg ∘ ... ∘ T_0
  float a = alpha, b = beta;
  #pragma unroll
  for (int off=1; off<16; off<<=1){
    float pa = __shfl_up(a, off, 16);
    float pb = __shfl_up(b, off, 16);
    if (seg >= off){ b = a*pb + b; a = a*pa; }
  }
  // exclusive: start value of this segment = P_{seg-1}(S0)
  float ea = __shfl_up(a, 1, 16);
  float eb = __shfl_up(b, 1, 16);
  float Sp = (seg == 0) ? S0 : (ea*S0 + eb);

  // output pass: out_c = S_c + x_c ; S <- (1+w)S - w*a    (16 serial steps)
  #pragma unroll
  for (int i=0; i<2; ++i){
    const u32* p = (const u32*)&d[i];
    float xs[8] = {xv[2*i].x, xv[2*i].y, xv[2*i].z, xv[2*i].w,
                   xv[2*i+1].x, xv[2*i+1].y, xv[2*i+1].z, xv[2*i+1].w};
    float os[8];
    #pragma unroll
    for (int k=0; k<4; ++k){
      u32 wv = p[k];
      int c = i*8 + k*2;
      float w_a = wseg[c];
      float w_b = wseg[c+1];
      float a_a = bf2f((u16)(wv & 0xFFFF));
      float a_b = bf2f((u16)(wv >> 16));
      os[k*2]   = Sp + xs[k*2];
      Sp = (1.f + w_a)*Sp - w_a*a_a;
      os[k*2+1] = Sp + xs[k*2+1];
      Sp = (1.f + w_b)*Sp - w_b*a_b;
    }
    float4 o0, o1;
    o0.x=os[0]; o0.y=os[1]; o0.z=os[2]; o0.w=os[3];
    o1.x=os[4]; o1.y=os[5]; o1.z=os[6]; o1.w=os[7];
    *(float4*)&out[cbase + i*8]     = o0;
    *(float4*)&out[cbase + i*8 + 4] = o1;
  }
}

extern "C" void kernel_launch(void* const* d_in, const int* in_sizes, int n_in,
                              void* d_out, int out_size, void* d_ws, size_t ws_size,
                              hipStream_t stream){
  const float* x  = (const float*)d_in[0];
  const float* w1 = (const float*)d_in[1];
  const float* b1 = (const float*)d_in[2];
  const float* w2 = (const float*)d_in[3];
  const float* b2 = (const float*)d_in[4];
  const float* w3 = (const float*)d_in[5];
  const float* b3 = (const float*)d_in[6];
  float* out = (float*)d_out;

  // workspace carve: B(relu'd) 32MB | Bout 32MB | W1T 32KB | W2T 288KB
  u16* B    = (u16*)d_ws;
  u16* Bout = B    + (size_t)NPIX*CH;
  u16* W1T  = Bout + (size_t)NPIX*CH;
  u16* W2T  = W1T  + 16384;

  hipLaunchKernelGGL(k_prep,   dim3(640),  dim3(256), 0, stream, w1, w2, W1T, W2T);
  hipLaunchKernelGGL(k_phase1, dim3(1024), dim3(256), 0, stream, x, W1T, b1, B);
  for (int s = 0; s < 4; ++s)
    hipLaunchKernelGGL(k_phase2, dim3(256), dim3(512), 0, stream, B, Bout, W2T, b2, s);
  hipLaunchKernelGGL(k_phase3, dim3(4096), dim3(256), 0, stream, Bout, w3, b3, x, out);
}